// Round 6
// baseline (245.772 us; speedup 1.0000x reference)
//
#include <hip/hip_runtime.h>

// ConvLSTM cell on MI355X (gfx950) — round 9.
// Implicit GEMM M=256 (4 gates x 64 oc), K=864 (96ch x 9 taps), N=131072.
// bf16 MFMA 32x32x16. Wave tile M=64 (og: 4 gates x 16 oc) x N=64 (row y0+nh),
// acc[fi][ns] = 64 AGPR. 512 thr = 8 waves, grid 1024, (512,4) -> 16 waves/CU.
// Round-9 change vs round-7/8: the 54 lockstep barrier phases were the
// bottleneck (~1770 cyc/phase wall vs ~450 cyc pipe work -> barrier+latency
// sawtooth). Now: B staged ONCE into LDS (50.7 KB, one __syncthreads), and A
// read DIRECTLY from global per phase (a_pk is 432 KB, L2/L1-resident; packed
// layout makes each A-frag a coalesced 1 KB global_load_dwordx4). Main loop
// has ZERO barriers: waves free-run, compiler pipelines A loads across the
// kk-unrolled window, 4 waves/SIMD de-phase to hide L2/LDS latency.
// LDS-read traffic: 2 ds_read_b128/phase/wave = 17 us/CU floor < 23 us MFMA.

#define B_   32
#define CIN  32
#define HC_  64
#define HH   64
#define WW   64

#define A_ELEMS (9 * 6 * 8 * 64 * 8)     // 221184 bf16 = 256 x 864 packed A
#define P_ROW   (12 * 66 * 8)            // shorts per P' row = 6336
#define AKK     4096                     // shorts per 1-kk A chunk (8 KB)
#define BLDS    25344                    // shorts of B in LDS (4 rows, 50688 B)

typedef __attribute__((ext_vector_type(8)))  short  short8;
typedef __attribute__((ext_vector_type(16))) float  floatx16;

struct PackArgs {
    const float* wx[4]; const float* wh[4];
    const float* bx[4]; const float* bh[4];
};

__device__ __forceinline__ short f2bf(float f) {
    unsigned u = __float_as_uint(f);
    u += 0x7FFFu + ((u >> 16) & 1u);     // round-to-nearest-even
    return (short)(u >> 16);
}

__device__ __forceinline__ void gl_lds16(const short* g, short* l) {
    __builtin_amdgcn_global_load_lds(
        (const __attribute__((address_space(1))) unsigned int*)g,
        (__attribute__((address_space(3))) unsigned int*)l, 16, 0, 0);
}

// ---- pack A: [tap 9][kk 6][s 8][lane 64][j 8] ------------------------------
// s = og*2+fi ; m32 = lane&31 ; gate = 2*fi + (m32>>4) ; oc = og*16 + (m32&15)
// c = kk*16 + (lane>>5)*8 + j  (A-operand: m = lane&31, k = (lane>>5)*8+j)
__global__ __launch_bounds__(256) void pack_weights(PackArgs pa, short* a_pk, float* bias) {
    int idx = blockIdx.x * 256 + threadIdx.x;
    if (idx < A_ELEMS) {
        int j    = idx & 7;
        int lane = (idx >> 3) & 63;
        int rest = idx >> 9;             // (tap*6 + kk)*8 + s
        int s    = rest & 7;
        int rest2 = rest >> 3;
        int kk   = rest2 % 6;
        int tap  = rest2 / 6;
        int og = s >> 1, fi = s & 1;
        int m32 = lane & 31;
        int gate = 2 * fi + (m32 >> 4);
        int oc   = og * 16 + (m32 & 15);
        int c    = kk * 16 + (lane >> 5) * 8 + j;
        int ky = tap / 3, kx = tap - 3 * ky;
        float v = (c < CIN)
            ? pa.wx[gate][((oc * CIN + c) * 3 + ky) * 3 + kx]
            : pa.wh[gate][((oc * HC_ + (c - CIN)) * 3 + ky) * 3 + kx];
        a_pk[idx] = f2bf(v);
    }
    if (idx < 256) {
        int gate = idx >> 6, oc = idx & 63;
        bias[idx] = pa.bx[gate][oc] + pa.bh[gate][oc];
    }
}

// ---- pack x||h -> P'[b][yy][pc 12][xx 66][8ch] bf16, zero borders ----------
__global__ __launch_bounds__(256) void pack_input(const float* __restrict__ x,
                                                  const float* __restrict__ h,
                                                  short* __restrict__ P) {
    const int yy = blockIdx.x, b = blockIdx.y;
    int4* prow4 = (int4*)(P + ((size_t)b * 66 + yy) * P_ROW);  // 792 chunks

    if (yy == 0 || yy == 65) {
        int4 z = {0, 0, 0, 0};
        for (int g = threadIdx.x; g < 792; g += 256) prow4[g] = z;
        return;
    }

    __shared__ short t[64 * 98];                     // [x][c], pad 96->98
    const int y = yy - 1;
    const int col = threadIdx.x & 63, cg = threadIdx.x >> 6;
    for (int c = cg; c < 96; c += 4) {
        float v = (c < CIN) ? x[((b * CIN + c) * HH + y) * WW + col]
                            : h[((b * HC_ + (c - CIN)) * HH + y) * WW + col];
        t[col * 98 + c] = f2bf(v);
    }
    __syncthreads();

    for (int g = threadIdx.x; g < 792; g += 256) {   // pc = g/66, xx = g%66
        int pc = g / 66, xx = g - 66 * pc;
        int4 val = {0, 0, 0, 0};
        if (xx >= 1 && xx <= 64) {
            const short* sp = &t[(xx - 1) * 98 + pc * 8];
            val.x = *(const int*)(sp + 0); val.y = *(const int*)(sp + 2);
            val.z = *(const int*)(sp + 4); val.w = *(const int*)(sp + 6);
        }
        prow4[g] = val;
    }
}

// ---- main: grid 1024 = (b 32)x(rowpair 32), 512 thr = 8 waves --------------
// wave = og(0..3) x nh(0..1). acc[fi][ns], 64 AGPR.
// LDS: B only, 4 P-rows x 6336 shorts (50688 B), staged once in prologue.
// Main loop: 9 taps x 6 kk, NO barriers. A frags from global (L1/L2),
// B frags ds_read_b128.
__global__ __launch_bounds__(512, 4) void convlstm_main(
    const short* __restrict__ P, const short* __restrict__ a_pk,
    const float* __restrict__ bias, const float* __restrict__ cell,
    float* __restrict__ out)
{
    __shared__ __align__(16) short lds[BLDS];        // 50688 B

    const int tid = threadIdx.x;
    const int b  = blockIdx.x >> 5;
    const int y0 = (blockIdx.x & 31) * 2;

    const int wv = tid >> 6, lane = tid & 63;
    const int ln31 = lane & 31, hg = lane >> 5;
    const int og = wv & 3, nh = wv >> 2;
    const int y = y0 + nh;

    floatx16 acc[2][2];
    #pragma unroll
    for (int fi = 0; fi < 2; ++fi)
        #pragma unroll
        for (int ns = 0; ns < 2; ++ns)
            #pragma unroll
            for (int q = 0; q < 16; ++q) acc[fi][ns][q] = 0.f;

    // per-wave A source: [tap][kk] stride 4096, + og*1024 + fi*512 + lane*8
    const short* Ag  = a_pk + og * 1024 + lane * 8;
    const int    b_rd = nh * 6336 + hg * 528 + ln31 * 8;

    // ---- prologue: stage B rows y0..y0+3 (3168 chunks / 512 thr) ---------
    {
        const short* Bsrc = P + ((size_t)(b * 66) + y0) * P_ROW;
        #pragma unroll
        for (int i = 0; i < 7; ++i) {
            int id = i * 512 + tid;
            if (id < 3168)
                gl_lds16(Bsrc + id * 8, lds + (i * 512 + wv * 64) * 8);
        }
    }
    __syncthreads();                                 // the ONLY barrier

    for (int tap = 0; tap < 9; ++tap) {
        const int ky = tap / 3, kx = tap % 3;
        const short* Bb = lds + b_rd + ky * 6336 + kx * 8;
        const short* Ac = Ag + tap * 6 * AKK;

        #pragma unroll
        for (int kk = 0; kk < 6; ++kk) {
            short8 a0 = *(const short8*)&Ac[kk * AKK];
            short8 a1 = *(const short8*)&Ac[kk * AKK + 512];
            short8 b0 = *(const short8*)&Bb[kk * 1056];
            short8 b1 = *(const short8*)&Bb[kk * 1056 + 256];
            acc[0][0] = __builtin_amdgcn_mfma_f32_32x32x16_bf16(a0, b0, acc[0][0], 0, 0, 0);
            acc[0][1] = __builtin_amdgcn_mfma_f32_32x32x16_bf16(a0, b1, acc[0][1], 0, 0, 0);
            acc[1][0] = __builtin_amdgcn_mfma_f32_32x32x16_bf16(a1, b0, acc[1][0], 0, 0, 0);
            acc[1][1] = __builtin_amdgcn_mfma_f32_32x32x16_bf16(a1, b1, acc[1][1], 0, 0, 0);
        }
    }

    // ---- lane-local LSTM epilogue --------------------------------------
    // C/D 32x32 map: col = ln31, row r32 = (r&3) + 4*hg + 8*(r>>2).
    // acc[fi][.] rows: r32<16 -> gate 2fi, oc16=r32 ; r32>=16 -> gate 2fi+1.
    const size_t plane = (size_t)B_ * HC_ * HH * WW;
    #pragma unroll
    for (int q = 0; q < 4; ++q)
    #pragma unroll
    for (int b8 = 0; b8 < 2; ++b8) {
        const int oc16 = q + 4 * hg + 8 * b8;
        const int oc = og * 16 + oc16;
        const float Bi = bias[oc],       Bf = bias[64 + oc];
        const float Bo = bias[128 + oc], Bg = bias[192 + oc];
        const int r_lo = q + 4 * b8, r_hi = q + 4 * (2 + b8);
        #pragma unroll
        for (int ns = 0; ns < 2; ++ns) {
            float zi = acc[0][ns][r_lo] + Bi;
            float zf = acc[0][ns][r_hi] + Bf;
            float zo = acc[1][ns][r_lo] + Bo;
            float zg = acc[1][ns][r_hi] + Bg;
            float ig = 1.f / (1.f + __expf(-zi));
            float fg = 1.f / (1.f + __expf(-zf));
            float sg = 1.f / (1.f + __expf(-zo));
            float e2 = __expf(2.f * zg);
            float gg = 1.f - 2.f / (e2 + 1.f);               // tanh(zg)
            const int x = ns * 32 + ln31;
            size_t off = ((size_t)(b * HC_ + oc) * HH + y) * WW + x;
            float cn = fg * cell[off] + ig * gg;
            float ec = __expf(2.f * cn);
            out[off] = sg * (1.f - 2.f / (ec + 1.f));        // h_new
            out[plane + off] = cn;                           // c_new
        }
    }
}

extern "C" void kernel_launch(void* const* d_in, const int* in_sizes, int n_in,
                              void* d_out, int out_size, void* d_ws, size_t ws_size,
                              hipStream_t stream) {
    PackArgs pa;
    pa.wx[0] = (const float*)d_in[3];  pa.bx[0] = (const float*)d_in[4];
    pa.wx[1] = (const float*)d_in[5];  pa.bx[1] = (const float*)d_in[6];
    pa.wx[2] = (const float*)d_in[7];  pa.bx[2] = (const float*)d_in[8];
    pa.wx[3] = (const float*)d_in[9];  pa.bx[3] = (const float*)d_in[10];
    pa.wh[0] = (const float*)d_in[11]; pa.bh[0] = (const float*)d_in[12];
    pa.wh[1] = (const float*)d_in[13]; pa.bh[1] = (const float*)d_in[14];
    pa.wh[2] = (const float*)d_in[15]; pa.bh[2] = (const float*)d_in[16];
    pa.wh[3] = (const float*)d_in[17]; pa.bh[3] = (const float*)d_in[18];

    short* a_pk = (short*)d_ws;                                    // 442368 B
    float* bias = (float*)((char*)d_ws + A_ELEMS * sizeof(short)); // 1024 B
    short* P    = (short*)((char*)d_ws + 443392);                  // 26.76 MB

    pack_weights<<<dim3(A_ELEMS / 256), dim3(256), 0, stream>>>(pa, a_pk, bias);
    pack_input <<<dim3(66, B_), dim3(256), 0, stream>>>(
        (const float*)d_in[0], (const float*)d_in[1], P);
    convlstm_main<<<dim3(B_ * 32), dim3(512), 0, stream>>>(
        P, a_pk, bias, (const float*)d_in[2], (float*)d_out);
}

// Round 7
// 227.011 us; speedup vs baseline: 1.0826x; 1.0826x over previous
//
#include <hip/hip_runtime.h>

// ConvLSTM cell on MI355X (gfx950) — round 10.
// Implicit GEMM M=256 (4 gates x 64 oc), K=864 (96ch x 9 taps), N=131072.
// bf16 MFMA 32x32x16. Wave tile M=64 (og: 4 gates x 16 oc) x N=64 (row y0+nh),
// acc[fi][ns] = 64 AGPR. 512 thr = 8 waves, grid 1024, (512,4), 2 blocks/CU.
// Round-10 vs round-7 (79.5us, MfmaUtil 32%): halve sequential phase count.
// R7 floor arithmetic: MFMA 23us, LDS-pipe 35us, but 108 sequential barrier
// phases x ~1770cyc wall (only ~770 pipe work) -> phase-overhead-bound.
// Changes: (1) B staged per-ky (2 rows = 25.3KB single buffer, restaged at
// the 2 ky boundaries) instead of 4-rows-once; (2) freed LDS lets A chunks
// double to 2-kk (16KB), TRIPLE-buffered (48KB), depth-2 counted vmcnt(2)
// prefetch. 27 phases of 8 ds_read_b128 + 8 MFMA. LDS 74.5KB -> 2 blocks/CU.
// FP accumulation order identical to R7. setprio(1) around MFMA clusters.

#define B_   32
#define CIN  32
#define HC_  64
#define HH   64
#define WW   64

#define A_ELEMS (9 * 6 * 8 * 64 * 8)     // 221184 bf16 = 256 x 864 packed A
#define P_ROW   (12 * 66 * 8)            // shorts per P' row = 6336
#define ACH     8192                     // shorts per 2-kk A chunk (16 KB)
#define BROWS   12672                    // shorts of B in LDS (2 rows)

typedef __attribute__((ext_vector_type(8)))  short  short8;
typedef __attribute__((ext_vector_type(16))) float  floatx16;

struct PackArgs {
    const float* wx[4]; const float* wh[4];
    const float* bx[4]; const float* bh[4];
};

__device__ __forceinline__ short f2bf(float f) {
    unsigned u = __float_as_uint(f);
    u += 0x7FFFu + ((u >> 16) & 1u);     // round-to-nearest-even
    return (short)(u >> 16);
}

__device__ __forceinline__ void gl_lds16(const short* g, short* l) {
    __builtin_amdgcn_global_load_lds(
        (const __attribute__((address_space(1))) unsigned int*)g,
        (__attribute__((address_space(3))) unsigned int*)l, 16, 0, 0);
}

// ---- pack A: [tap 9][kk 6][s 8][lane 64][j 8] ------------------------------
// s = og*2+fi ; m32 = lane&31 ; gate = 2*fi + (m32>>4) ; oc = og*16 + (m32&15)
// c = kk*16 + (lane>>5)*8 + j  (A-operand: m = lane&31, k = (lane>>5)*8+j)
__global__ __launch_bounds__(256) void pack_weights(PackArgs pa, short* a_pk, float* bias) {
    int idx = blockIdx.x * 256 + threadIdx.x;
    if (idx < A_ELEMS) {
        int j    = idx & 7;
        int lane = (idx >> 3) & 63;
        int rest = idx >> 9;             // (tap*6 + kk)*8 + s
        int s    = rest & 7;
        int rest2 = rest >> 3;
        int kk   = rest2 % 6;
        int tap  = rest2 / 6;
        int og = s >> 1, fi = s & 1;
        int m32 = lane & 31;
        int gate = 2 * fi + (m32 >> 4);
        int oc   = og * 16 + (m32 & 15);
        int c    = kk * 16 + (lane >> 5) * 8 + j;
        int ky = tap / 3, kx = tap - 3 * ky;
        float v = (c < CIN)
            ? pa.wx[gate][((oc * CIN + c) * 3 + ky) * 3 + kx]
            : pa.wh[gate][((oc * HC_ + (c - CIN)) * 3 + ky) * 3 + kx];
        a_pk[idx] = f2bf(v);
    }
    if (idx < 256) {
        int gate = idx >> 6, oc = idx & 63;
        bias[idx] = pa.bx[gate][oc] + pa.bh[gate][oc];
    }
}

// ---- pack x||h -> P'[b][yy][pc 12][xx 66][8ch] bf16, zero borders ----------
__global__ __launch_bounds__(256) void pack_input(const float* __restrict__ x,
                                                  const float* __restrict__ h,
                                                  short* __restrict__ P) {
    const int yy = blockIdx.x, b = blockIdx.y;
    int4* prow4 = (int4*)(P + ((size_t)b * 66 + yy) * P_ROW);  // 792 chunks

    if (yy == 0 || yy == 65) {
        int4 z = {0, 0, 0, 0};
        for (int g = threadIdx.x; g < 792; g += 256) prow4[g] = z;
        return;
    }

    __shared__ short t[64 * 98];                     // [x][c], pad 96->98
    const int y = yy - 1;
    const int col = threadIdx.x & 63, cg = threadIdx.x >> 6;
    for (int c = cg; c < 96; c += 4) {
        float v = (c < CIN) ? x[((b * CIN + c) * HH + y) * WW + col]
                            : h[((b * HC_ + (c - CIN)) * HH + y) * WW + col];
        t[col * 98 + c] = f2bf(v);
    }
    __syncthreads();

    for (int g = threadIdx.x; g < 792; g += 256) {   // pc = g/66, xx = g%66
        int pc = g / 66, xx = g - 66 * pc;
        int4 val = {0, 0, 0, 0};
        if (xx >= 1 && xx <= 64) {
            const short* sp = &t[(xx - 1) * 98 + pc * 8];
            val.x = *(const int*)(sp + 0); val.y = *(const int*)(sp + 2);
            val.z = *(const int*)(sp + 4); val.w = *(const int*)(sp + 6);
        }
        prow4[g] = val;
    }
}

// ---- main: grid 1024 = (b 32)x(rowpair 32), 512 thr = 8 waves --------------
// wave = og(0..3) x nh(0..1). acc[fi][ns], 64 AGPR.
// LDS: B 2 rows (y0+ky, y0+ky+1; LDS row index = nh) + A 3 x 2kk bufs.
// 27 phases (c = tap*3 + kkpair): depth-2 A prefetch, counted vmcnt(2);
// B restaged at c = 9, 18 with a mid-phase counted wait.
__global__ __launch_bounds__(512, 4) void convlstm_main(
    const short* __restrict__ P, const short* __restrict__ a_pk,
    const float* __restrict__ bias, const float* __restrict__ cell,
    float* __restrict__ out)
{
    __shared__ __align__(16) short lds[BROWS + 3 * ACH];   // 74496 B

    const int tid = threadIdx.x;
    const int b  = blockIdx.x >> 5;
    const int y0 = (blockIdx.x & 31) * 2;

    const int wv = tid >> 6, lane = tid & 63;
    const int ln31 = lane & 31, hg = lane >> 5;
    const int og = wv & 3, nh = wv >> 2;
    const int y = y0 + nh;

    floatx16 acc[2][2];
    #pragma unroll
    for (int fi = 0; fi < 2; ++fi)
        #pragma unroll
        for (int ns = 0; ns < 2; ++ns)
            #pragma unroll
            for (int q = 0; q < 16; ++q) acc[fi][ns][q] = 0.f;

    short* ldsB = lds;                   // 2 x 6336 shorts
    short* As   = lds + BROWS;           // 3 x 8192 shorts

    const int a_rd = og * 1024 + lane * 8;              // + buf*8192 + kkl*4096 (+512 fi)
    const int b_rd = nh * 6336 + hg * 528 + ln31 * 8;   // + kk*1056 + kx*8 (+256 ns)

    // ---- staging helpers (instr counts per thread: B = 3 (+1 for tid>=464),
    //      A = 2) — vmcnt waits below count A instrs only (B always older).
    #define STAGE_B(KY) do {                                                   \
        const short* Bs_ = P + ((size_t)(b * 66) + y0 + (KY)) * P_ROW;         \
        _Pragma("unroll")                                                      \
        for (int i_ = 0; i_ < 3; ++i_)                                         \
            gl_lds16(Bs_ + (i_ * 512 + tid) * 8, ldsB + (i_ * 512 + wv * 64) * 8); \
        if (tid >= 464)                                                        \
            gl_lds16(Bs_ + (1520 + lane) * 8, ldsB + 1520 * 8);                \
    } while (0)

    #define STAGE_A(C) do {                                                    \
        const short* s_ = a_pk + (C) * ACH;                                    \
        short* d_ = As + ((C) % 3) * ACH;                                      \
        _Pragma("unroll")                                                      \
        for (int i_ = 0; i_ < 2; ++i_)                                         \
            gl_lds16(s_ + (i_ * 512 + tid) * 8, d_ + (i_ * 512 + wv * 64) * 8);\
    } while (0)

    // ---- prologue: B(ky0) + A0 + A1; wait until only A1 (2 instrs) in flight
    STAGE_B(0);
    STAGE_A(0);
    STAGE_A(1);
    asm volatile("s_waitcnt vmcnt(2)" ::: "memory");
    __builtin_amdgcn_s_barrier();
    __builtin_amdgcn_sched_barrier(0);

    #pragma unroll
    for (int c = 0; c < 27; ++c) {
        const int tap = c / 3, ky = tap / 3, kx = tap % 3;
        const bool bdry = (c == 9 || c == 18);

        if (bdry) STAGE_B(ky);           // issued first (older than A below)
        if (c < 25) STAGE_A(c + 2);
        if (bdry) {                      // B + A(c+1) landed; A(c+2) in flight
            asm volatile("s_waitcnt vmcnt(2)" ::: "memory");
            __builtin_amdgcn_s_barrier();
            __builtin_amdgcn_sched_barrier(0);
        }

        const short* Ab = As + (c % 3) * ACH + a_rd;
        const short* Bb = ldsB + b_rd + kx * 8;

        #pragma unroll
        for (int kkl = 0; kkl < 2; ++kkl) {
            const int kk = 2 * (c % 3) + kkl;
            short8 a0 = *(const short8*)&Ab[kkl * 4096];
            short8 a1 = *(const short8*)&Ab[kkl * 4096 + 512];
            short8 b0 = *(const short8*)&Bb[kk * 1056];
            short8 b1 = *(const short8*)&Bb[kk * 1056 + 256];
            __builtin_amdgcn_s_setprio(1);
            acc[0][0] = __builtin_amdgcn_mfma_f32_32x32x16_bf16(a0, b0, acc[0][0], 0, 0, 0);
            acc[0][1] = __builtin_amdgcn_mfma_f32_32x32x16_bf16(a0, b1, acc[0][1], 0, 0, 0);
            acc[1][0] = __builtin_amdgcn_mfma_f32_32x32x16_bf16(a1, b0, acc[1][0], 0, 0, 0);
            acc[1][1] = __builtin_amdgcn_mfma_f32_32x32x16_bf16(a1, b1, acc[1][1], 0, 0, 0);
            __builtin_amdgcn_s_setprio(0);
        }

        // close phase: counted wait — A(c+1) landed, A(c+2) stays in flight
        if (c < 25)       asm volatile("s_waitcnt vmcnt(2)" ::: "memory");
        else if (c == 25) asm volatile("s_waitcnt vmcnt(0)" ::: "memory");
        if (c < 26) {
            __builtin_amdgcn_s_barrier();
            __builtin_amdgcn_sched_barrier(0);
        }
    }
    #undef STAGE_A
    #undef STAGE_B

    // ---- lane-local LSTM epilogue --------------------------------------
    // C/D 32x32 map: col = ln31, row r32 = (r&3) + 4*hg + 8*(r>>2).
    // acc[fi][.] rows: r32<16 -> gate 2fi, oc16=r32 ; r32>=16 -> gate 2fi+1.
    const size_t plane = (size_t)B_ * HC_ * HH * WW;
    #pragma unroll
    for (int q = 0; q < 4; ++q)
    #pragma unroll
    for (int b8 = 0; b8 < 2; ++b8) {
        const int oc16 = q + 4 * hg + 8 * b8;
        const int oc = og * 16 + oc16;
        const float Bi = bias[oc],       Bf = bias[64 + oc];
        const float Bo = bias[128 + oc], Bg = bias[192 + oc];
        const int r_lo = q + 4 * b8, r_hi = q + 4 * (2 + b8);
        #pragma unroll
        for (int ns = 0; ns < 2; ++ns) {
            float zi = acc[0][ns][r_lo] + Bi;
            float zf = acc[0][ns][r_hi] + Bf;
            float zo = acc[1][ns][r_lo] + Bo;
            float zg = acc[1][ns][r_hi] + Bg;
            float ig = 1.f / (1.f + __expf(-zi));
            float fg = 1.f / (1.f + __expf(-zf));
            float sg = 1.f / (1.f + __expf(-zo));
            float e2 = __expf(2.f * zg);
            float gg = 1.f - 2.f / (e2 + 1.f);               // tanh(zg)
            const int x = ns * 32 + ln31;
            size_t off = ((size_t)(b * HC_ + oc) * HH + y) * WW + x;
            float cn = fg * cell[off] + ig * gg;
            float ec = __expf(2.f * cn);
            out[off] = sg * (1.f - 2.f / (ec + 1.f));        // h_new
            out[plane + off] = cn;                           // c_new
        }
    }
}

extern "C" void kernel_launch(void* const* d_in, const int* in_sizes, int n_in,
                              void* d_out, int out_size, void* d_ws, size_t ws_size,
                              hipStream_t stream) {
    PackArgs pa;
    pa.wx[0] = (const float*)d_in[3];  pa.bx[0] = (const float*)d_in[4];
    pa.wx[1] = (const float*)d_in[5];  pa.bx[1] = (const float*)d_in[6];
    pa.wx[2] = (const float*)d_in[7];  pa.bx[2] = (const float*)d_in[8];
    pa.wx[3] = (const float*)d_in[9];  pa.bx[3] = (const float*)d_in[10];
    pa.wh[0] = (const float*)d_in[11]; pa.bh[0] = (const float*)d_in[12];
    pa.wh[1] = (const float*)d_in[13]; pa.bh[1] = (const float*)d_in[14];
    pa.wh[2] = (const float*)d_in[15]; pa.bh[2] = (const float*)d_in[16];
    pa.wh[3] = (const float*)d_in[17]; pa.bh[3] = (const float*)d_in[18];

    short* a_pk = (short*)d_ws;                                    // 442368 B
    float* bias = (float*)((char*)d_ws + A_ELEMS * sizeof(short)); // 1024 B
    short* P    = (short*)((char*)d_ws + 443392);                  // 26.76 MB

    pack_weights<<<dim3(A_ELEMS / 256), dim3(256), 0, stream>>>(pa, a_pk, bias);
    pack_input <<<dim3(66, B_), dim3(256), 0, stream>>>(
        (const float*)d_in[0], (const float*)d_in[1], P);
    convlstm_main<<<dim3(B_ * 32), dim3(512), 0, stream>>>(
        P, a_pk, bias, (const float*)d_in[2], (float*)d_out);
}

// Round 8
// 226.929 us; speedup vs baseline: 1.0830x; 1.0004x over previous
//
#include <hip/hip_runtime.h>

// ConvLSTM cell on MI355X (gfx950) — round 11.
// Implicit GEMM M=256 (4 gates x 64 oc), K=864 (96ch x 9 taps), N=131072.
// bf16 MFMA 32x32x16. Wave tile M=64 (og: 4 gates x 16 oc) x N=64 (1 row),
// acc[fi][ns] = 64 AGPR.
// Round-11 vs R7/R10 (~80us, MfmaUtil 30%, LDS pipe 43% busy): the per-phase
// barrier synchronized all waves into read-burst/MFMA-burst alternation; the
// barrier only protected the SHARED A ring rotation. Fix: PRIVATE per-wave A
// rings. A wave's fragment slice (og*1024+fi*512+lane*8) is exactly the 1KB a
// single global_load_lds writes, so each wave stages its own slices into its
// own 4-slot ring and orders reads with its OWN vmcnt. ZERO barriers in the
// 54-phase loop; waves free-run and self-stagger -> continuous LDS pressure.
// Block = 4 waves (256 thr), 1 output row; B = 3 P-rows (38 KB) staged once
// (single __syncthreads); A = 4 waves x 4 x 2KB (24.6 KB). LDS 62.6 KB ->
// 2 blocks/CU, grid 2048. Depth-3 prefetch, steady vmcnt(6). FP accumulation
// order identical to R7/R10. A L2 traffic 2x (885 MB total) - async-hidden.

#define B_   32
#define CIN  32
#define HC_  64
#define HH   64
#define WW   64

#define A_ELEMS (9 * 6 * 8 * 64 * 8)     // 221184 bf16 = 256 x 864 packed A
#define P_ROW   (12 * 66 * 8)            // shorts per P' row = 6336
#define BLDS    (3 * P_ROW)              // 19008 shorts = 38016 B (3 rows)
#define ARING   1024                     // shorts per ring slot (2 KB, og slice)

typedef __attribute__((ext_vector_type(8)))  short  short8;
typedef __attribute__((ext_vector_type(16))) float  floatx16;

struct PackArgs {
    const float* wx[4]; const float* wh[4];
    const float* bx[4]; const float* bh[4];
};

__device__ __forceinline__ short f2bf(float f) {
    unsigned u = __float_as_uint(f);
    u += 0x7FFFu + ((u >> 16) & 1u);     // round-to-nearest-even
    return (short)(u >> 16);
}

__device__ __forceinline__ void gl_lds16(const short* g, short* l) {
    __builtin_amdgcn_global_load_lds(
        (const __attribute__((address_space(1))) unsigned int*)g,
        (__attribute__((address_space(3))) unsigned int*)l, 16, 0, 0);
}

// ---- pack A: [tap 9][kk 6][s 8][lane 64][j 8] ------------------------------
// s = og*2+fi ; m32 = lane&31 ; gate = 2*fi + (m32>>4) ; oc = og*16 + (m32&15)
// c = kk*16 + (lane>>5)*8 + j  (A-operand: m = lane&31, k = (lane>>5)*8+j)
__global__ __launch_bounds__(256) void pack_weights(PackArgs pa, short* a_pk, float* bias) {
    int idx = blockIdx.x * 256 + threadIdx.x;
    if (idx < A_ELEMS) {
        int j    = idx & 7;
        int lane = (idx >> 3) & 63;
        int rest = idx >> 9;             // (tap*6 + kk)*8 + s
        int s    = rest & 7;
        int rest2 = rest >> 3;
        int kk   = rest2 % 6;
        int tap  = rest2 / 6;
        int og = s >> 1, fi = s & 1;
        int m32 = lane & 31;
        int gate = 2 * fi + (m32 >> 4);
        int oc   = og * 16 + (m32 & 15);
        int c    = kk * 16 + (lane >> 5) * 8 + j;
        int ky = tap / 3, kx = tap - 3 * ky;
        float v = (c < CIN)
            ? pa.wx[gate][((oc * CIN + c) * 3 + ky) * 3 + kx]
            : pa.wh[gate][((oc * HC_ + (c - CIN)) * 3 + ky) * 3 + kx];
        a_pk[idx] = f2bf(v);
    }
    if (idx < 256) {
        int gate = idx >> 6, oc = idx & 63;
        bias[idx] = pa.bx[gate][oc] + pa.bh[gate][oc];
    }
}

// ---- pack x||h -> P'[b][yy][pc 12][xx 66][8ch] bf16, zero borders ----------
__global__ __launch_bounds__(256) void pack_input(const float* __restrict__ x,
                                                  const float* __restrict__ h,
                                                  short* __restrict__ P) {
    const int yy = blockIdx.x, b = blockIdx.y;
    int4* prow4 = (int4*)(P + ((size_t)b * 66 + yy) * P_ROW);  // 792 chunks

    if (yy == 0 || yy == 65) {
        int4 z = {0, 0, 0, 0};
        for (int g = threadIdx.x; g < 792; g += 256) prow4[g] = z;
        return;
    }

    __shared__ short t[64 * 98];                     // [x][c], pad 96->98
    const int y = yy - 1;
    const int col = threadIdx.x & 63, cg = threadIdx.x >> 6;
    for (int c = cg; c < 96; c += 4) {
        float v = (c < CIN) ? x[((b * CIN + c) * HH + y) * WW + col]
                            : h[((b * HC_ + (c - CIN)) * HH + y) * WW + col];
        t[col * 98 + c] = f2bf(v);
    }
    __syncthreads();

    for (int g = threadIdx.x; g < 792; g += 256) {   // pc = g/66, xx = g%66
        int pc = g / 66, xx = g - 66 * pc;
        int4 val = {0, 0, 0, 0};
        if (xx >= 1 && xx <= 64) {
            const short* sp = &t[(xx - 1) * 98 + pc * 8];
            val.x = *(const int*)(sp + 0); val.y = *(const int*)(sp + 2);
            val.z = *(const int*)(sp + 4); val.w = *(const int*)(sp + 6);
        }
        prow4[g] = val;
    }
}

// ---- main: grid 2048 = (b 32)x(row 64), 256 thr = 4 waves (wv = og) --------
// LDS: [B 3 rows x 6336][A: wave wv -> 4-slot private ring of 1024 shorts].
// 54 phases (c = tap*6+kk): wave stages ITS og-slice of chunk c+3 into its
// own ring slot (2 x gl_lds, wave-uniform dst), waits vmcnt(6) (own loads
// only), 4 ds_read_b128, 4 MFMA. No s_barrier anywhere in the loop.
__global__ __launch_bounds__(256, 2) void convlstm_main(
    const short* __restrict__ P, const short* __restrict__ a_pk,
    const float* __restrict__ bias, const float* __restrict__ cell,
    float* __restrict__ out)
{
    __shared__ __align__(16) short lds[BLDS + 4 * 4 * ARING];   // 62592 B

    const int tid = threadIdx.x;
    const int b = blockIdx.x >> 6;
    const int y = blockIdx.x & 63;

    const int wv = tid >> 6, lane = tid & 63;        // wv = og
    const int ln31 = lane & 31, hg = lane >> 5;
    const int og = wv;

    floatx16 acc[2][2];
    #pragma unroll
    for (int fi = 0; fi < 2; ++fi)
        #pragma unroll
        for (int ns = 0; ns < 2; ++ns)
            #pragma unroll
            for (int q = 0; q < 16; ++q) acc[fi][ns][q] = 0.f;

    short* Aring = lds + BLDS + wv * (4 * ARING);    // private 4-slot ring
    const int b_rd = hg * 528 + ln31 * 8;            // + ky*6336 + kk*1056 + kx*8

    // ---- prologue: B rows y..y+2 (2376 chunks / 256 thr) + A chunks 0..2 --
    {
        const short* Bsrc = P + ((size_t)(b * 66) + y) * P_ROW;
        #pragma unroll
        for (int i = 0; i < 10; ++i) {
            int id = i * 256 + tid;
            if (id < 2376)
                gl_lds16(Bsrc + id * 8, lds + (i * 256 + wv * 64) * 8);
        }
        #pragma unroll
        for (int ck = 0; ck < 3; ++ck) {
            const short* src = a_pk + ck * 4096 + og * 1024 + lane * 8;
            gl_lds16(src,       Aring + ck * ARING);
            gl_lds16(src + 512, Aring + ck * ARING + 512);
        }
    }
    __syncthreads();                                 // the ONLY barrier

    #pragma unroll
    for (int c = 0; c < 54; ++c) {
        const int tap = c / 6, kk = c % 6;
        const int ky = tap / 3, kx = tap % 3;

        // stage own og-slice of chunk c+3 into own ring slot (c+3)%4
        if (c < 51) {
            const short* src = a_pk + (c + 3) * 4096 + og * 1024 + lane * 8;
            short* dst = Aring + ((c + 3) & 3) * ARING;
            gl_lds16(src,       dst);
            gl_lds16(src + 512, dst + 512);
        }

        // own-load-only wait: chunk c landed; c+1..c+3 may stay in flight
        if (c < 51)       asm volatile("s_waitcnt vmcnt(6)" ::: "memory");
        else if (c == 51) asm volatile("s_waitcnt vmcnt(4)" ::: "memory");
        else if (c == 52) asm volatile("s_waitcnt vmcnt(2)" ::: "memory");
        else              asm volatile("s_waitcnt vmcnt(0)" ::: "memory");

        const short* Ab = Aring + (c & 3) * ARING + lane * 8;
        const short* Bb = lds + b_rd + ky * 6336 + kk * 1056 + kx * 8;

        short8 a0 = *(const short8*)&Ab[0];
        short8 a1 = *(const short8*)&Ab[512];
        short8 b0 = *(const short8*)&Bb[0];
        short8 b1 = *(const short8*)&Bb[256];

        __builtin_amdgcn_s_setprio(1);
        acc[0][0] = __builtin_amdgcn_mfma_f32_32x32x16_bf16(a0, b0, acc[0][0], 0, 0, 0);
        acc[0][1] = __builtin_amdgcn_mfma_f32_32x32x16_bf16(a0, b1, acc[0][1], 0, 0, 0);
        acc[1][0] = __builtin_amdgcn_mfma_f32_32x32x16_bf16(a1, b0, acc[1][0], 0, 0, 0);
        acc[1][1] = __builtin_amdgcn_mfma_f32_32x32x16_bf16(a1, b1, acc[1][1], 0, 0, 0);
        __builtin_amdgcn_s_setprio(0);
    }

    // ---- lane-local LSTM epilogue --------------------------------------
    // C/D 32x32 map: col = ln31, row r32 = (r&3) + 4*hg + 8*(r>>2).
    // acc[fi][.] rows: r32<16 -> gate 2fi, oc16=r32 ; r32>=16 -> gate 2fi+1.
    const size_t plane = (size_t)B_ * HC_ * HH * WW;
    #pragma unroll
    for (int q = 0; q < 4; ++q)
    #pragma unroll
    for (int b8 = 0; b8 < 2; ++b8) {
        const int oc16 = q + 4 * hg + 8 * b8;
        const int oc = og * 16 + oc16;
        const float Bi = bias[oc],       Bf = bias[64 + oc];
        const float Bo = bias[128 + oc], Bg = bias[192 + oc];
        const int r_lo = q + 4 * b8, r_hi = q + 4 * (2 + b8);
        #pragma unroll
        for (int ns = 0; ns < 2; ++ns) {
            float zi = acc[0][ns][r_lo] + Bi;
            float zf = acc[0][ns][r_hi] + Bf;
            float zo = acc[1][ns][r_lo] + Bo;
            float zg = acc[1][ns][r_hi] + Bg;
            float ig = 1.f / (1.f + __expf(-zi));
            float fg = 1.f / (1.f + __expf(-zf));
            float sg = 1.f / (1.f + __expf(-zo));
            float e2 = __expf(2.f * zg);
            float gg = 1.f - 2.f / (e2 + 1.f);               // tanh(zg)
            const int x = ns * 32 + ln31;
            size_t off = ((size_t)(b * HC_ + oc) * HH + y) * WW + x;
            float cn = fg * cell[off] + ig * gg;
            float ec = __expf(2.f * cn);
            out[off] = sg * (1.f - 2.f / (ec + 1.f));        // h_new
            out[plane + off] = cn;                           // c_new
        }
    }
}

extern "C" void kernel_launch(void* const* d_in, const int* in_sizes, int n_in,
                              void* d_out, int out_size, void* d_ws, size_t ws_size,
                              hipStream_t stream) {
    PackArgs pa;
    pa.wx[0] = (const float*)d_in[3];  pa.bx[0] = (const float*)d_in[4];
    pa.wx[1] = (const float*)d_in[5];  pa.bx[1] = (const float*)d_in[6];
    pa.wx[2] = (const float*)d_in[7];  pa.bx[2] = (const float*)d_in[8];
    pa.wx[3] = (const float*)d_in[9];  pa.bx[3] = (const float*)d_in[10];
    pa.wh[0] = (const float*)d_in[11]; pa.bh[0] = (const float*)d_in[12];
    pa.wh[1] = (const float*)d_in[13]; pa.bh[1] = (const float*)d_in[14];
    pa.wh[2] = (const float*)d_in[15]; pa.bh[2] = (const float*)d_in[16];
    pa.wh[3] = (const float*)d_in[17]; pa.bh[3] = (const float*)d_in[18];

    short* a_pk = (short*)d_ws;                                    // 442368 B
    float* bias = (float*)((char*)d_ws + A_ELEMS * sizeof(short)); // 1024 B
    short* P    = (short*)((char*)d_ws + 443392);                  // 26.76 MB

    pack_weights<<<dim3(A_ELEMS / 256), dim3(256), 0, stream>>>(pa, a_pk, bias);
    pack_input <<<dim3(66, B_), dim3(256), 0, stream>>>(
        (const float*)d_in[0], (const float*)d_in[1], P);
    convlstm_main<<<dim3(B_ * 64), dim3(256), 0, stream>>>(
        P, a_pk, bias, (const float*)d_in[2], (float*)d_out);
}